// Round 6
// baseline (146.527 us; speedup 1.0000x reference)
//
#include <hip/hip_runtime.h>
#include <hip/hip_fp16.h>
#include <stdint.h>

// ---------------------------------------------------------------------------
// ThreeBodyLayer fused kernel v5 (MI355X / gfx950)
//
// All-f16 MFMA pipeline, log2-domain softplus (see v4b header for algebra).
// v5 vs v4b (48us/dispatch, 4 waves/SIMD, VALUBusy 43%):
//  - BPB 64->32, grid 1024; LDS = T only (53.9 KB) -> 2 blocks/CU = 8 w/SIMD
//  - W1^T/W2^T (f16, scaled) + b1/b2/W3 consts pre-converted into d_ws by a
//    tiny prep kernel; main kernel reads them as L2-hot global loads
//  - Phase 1 = 26-job table over 16 waves; Phase 2 = 60 units over 16 waves
// ---------------------------------------------------------------------------

typedef __attribute__((ext_vector_type(8))) _Float16 f16x8;
typedef __attribute__((ext_vector_type(2))) __fp16   fp16v2;   // cvt_pkrtz ret
typedef __attribute__((ext_vector_type(4))) float    f32x4;
typedef __attribute__((ext_vector_type(4))) unsigned int u32x4;

constexpr int   BPB       = 32;       // batch elems per block
constexpr int   NT        = 1024;     // 16 waves
constexpr int   T_STRIDE  = 1680;     // bytes per b: 13*128 + 16 pad (16B aligned)
constexpr int   Y_OFF     = BPB * T_STRIDE;   // 53760
constexpr int   LDS_BYTES = Y_OFF + 128;      // 53888 -> 2 blocks/CU

// d_ws layout (bytes)
constexpr int   WS_W1T   = 0;         // 12288 f16 : (slab*64+n)*64 + d
constexpr int   WS_W2T   = 24576;     //  2048 f16 : m*64 + k
constexpr int   WS_B1    = 28672;     //    64 f32 : b1 * L2E
constexpr int   WS_B2    = 28928;     //    32 f32 : b2 * L2E
constexpr int   WS_W3    = 29056;     //    32 f32 : W3 * LN2
constexpr int   WS_BYTES = 29184;

constexpr float L2E = 1.4426950408889634f;
constexpr float LN2 = 0.6931471805599453f;

// PAIRS i/j packed 3 bits per pair (15 pairs)
constexpr unsigned long long I_BITS =
  (0ull<<0)|(0ull<<3)|(0ull<<6)|(0ull<<9)|(0ull<<12)|
  (1ull<<15)|(1ull<<18)|(1ull<<21)|(1ull<<24)|
  (2ull<<27)|(2ull<<30)|(2ull<<33)|
  (3ull<<36)|(3ull<<39)|(4ull<<42);
constexpr unsigned long long J_BITS =
  (1ull<<0)|(2ull<<3)|(3ull<<6)|(4ull<<9)|(5ull<<12)|
  (2ull<<15)|(3ull<<18)|(4ull<<21)|(5ull<<24)|
  (3ull<<27)|(4ull<<30)|(5ull<<33)|
  (4ull<<36)|(5ull<<39)|(5ull<<42);

__device__ __forceinline__ float sp2(float s) {       // log2(1+exp2(s))
  float t = __builtin_amdgcn_exp2f(s);
  return __builtin_amdgcn_logf(1.0f + t);             // v_log_f32 = log2
}

__device__ __forceinline__ __half2 h1pair(__half2 u, __half2 a, __half2 b,
                                          __half2 one2) {
  __half2 s = __hadd2(__hadd2(u, a), b);
  __half2 t = h2exp2(s);                              // |s|<~8 -> safe in f16
  return h2log2(__hadd2(one2, t));
}

// ------------------------- prep: weights -> d_ws ---------------------------
__global__ __launch_bounds__(256)
void prep(const float* __restrict__ W1, const float* __restrict__ b1,
          const float* __restrict__ W2, const float* __restrict__ b2,
          const float* __restrict__ W3, char* __restrict__ ws)
{
  const int t = (int)(blockIdx.x * blockDim.x + threadIdx.x);   // 0..16383
  uint16_t* w1t = (uint16_t*)(ws + WS_W1T);
  uint16_t* w2t = (uint16_t*)(ws + WS_W2T);
  float*    b1s = (float*)(ws + WS_B1);
  float*    b2s = (float*)(ws + WS_B2);
  float*    w3s = (float*)(ws + WS_W3);
  if (t < 12288) {
    const int d = t >> 6, n = t & 63;                 // W1 is [d=192][n=64]
    const int slab = d >> 6;
    w1t[(slab * 64 + n) * 64 + (d & 63)] =
        __half_as_ushort(__float2half(W1[t] * L2E));
  } else if (t < 14336) {
    const int e = t - 12288;                          // W2 is [k=64][m=32]
    const int k = e >> 5, m = e & 31;
    w2t[m * 64 + k] = __half_as_ushort(__float2half(W2[e]));
  } else if (t < 14400) {
    b1s[t - 14336] = b1[t - 14336] * L2E;
  } else if (t < 14432) {
    b2s[t - 14400] = b2[t - 14400] * L2E;
  } else if (t < 14464) {
    w3s[t - 14432] = W3[t - 14432] * LN2;
  }
}

// ------------------------------ main kernel --------------------------------
__global__ __launch_bounds__(NT, 8)
void tb_fused(const float* __restrict__ core, const float* __restrict__ ligs,
              const float* __restrict__ b3,   const char* __restrict__ ws,
              float* __restrict__ out)
{
  extern __shared__ char smem[];
  const int tid  = (int)threadIdx.x;
  const int lane = tid & 63;
  const int ln   = lane & 15;        // fragment column
  const int qd   = lane >> 4;        // fragment quad
  const int wv   = __builtin_amdgcn_readfirstlane(tid >> 6);  // 0..15
  const int b0   = (int)blockIdx.x * BPB;

  const uint16_t* w1t = (const uint16_t*)(ws + WS_W1T);
  const uint16_t* w2t = (const uint16_t*)(ws + WS_W2T);
  const float*    b1s = (const float*)(ws + WS_B1);
  const float*    b2s = (const float*)(ws + WS_B2);
  const float*    w3s = (const float*)(ws + WS_W3);

  float* yred = (float*)(smem + Y_OFF);
  if (tid < BPB) yred[tid] = 0.0f;

  // ------------- Phase 1: 26 jobs over 16 waves ---------------------------
  // j<2: xr=0 sl=0 trow=0 mt=j ; j>=2: e=j-2: xr=e/4+1, sl=1+((e>>1)&1), mt=e&1
  #pragma unroll 1
  for (int jj = 0; jj < 2; ++jj) {
    const int j = wv + 16 * jj;
    if (j >= 26) break;                               // wave-uniform
    int xr, sl, mt, trow;
    if (j < 2)  { xr = 0; sl = 0; mt = j; trow = 0; }
    else        { const int e = j - 2; xr = (e >> 2) + 1; sl = 1 + ((e >> 1) & 1);
                  mt = e & 1; trow = (sl == 1) ? xr : 6 + xr; }

    const float* src = (xr == 0)
        ? (core + (size_t)(b0 + mt * 16 + ln) * 64)
        : (ligs + ((size_t)(b0 + mt * 16 + ln) * 6 + (size_t)(xr - 1)) * 64);

    union AF { f16x8 v; fp16v2 p[4]; } Afr[2];
    #pragma unroll
    for (int ks = 0; ks < 2; ++ks) {
      const float4 f0 = *(const float4*)(src + ks * 32 + qd * 8);
      const float4 f1 = *(const float4*)(src + ks * 32 + qd * 8 + 4);
      Afr[ks].p[0] = __builtin_amdgcn_cvt_pkrtz(f0.x, f0.y);
      Afr[ks].p[1] = __builtin_amdgcn_cvt_pkrtz(f0.z, f0.w);
      Afr[ks].p[2] = __builtin_amdgcn_cvt_pkrtz(f1.x, f1.y);
      Afr[ks].p[3] = __builtin_amdgcn_cvt_pkrtz(f1.z, f1.w);
    }

    #pragma unroll
    for (int nt = 0; nt < 4; ++nt) {
      f32x4 c = {0.f, 0.f, 0.f, 0.f};
      #pragma unroll
      for (int ks = 0; ks < 2; ++ks) {
        const f16x8 Bf = *(const f16x8*)(w1t +
            (sl * 64 + nt * 16 + ln) * 64 + ks * 32 + qd * 8);
        c = __builtin_amdgcn_mfma_f32_16x16x32_f16(Afr[ks].v, Bf, c, 0, 0, 0);
      }
      const float bias = (trow == 0) ? b1s[nt * 16 + ln] : 0.0f;
      #pragma unroll
      for (int reg = 0; reg < 4; ++reg) {
        const int b = mt * 16 + qd * 4 + reg;         // C row = batch-local b
        *(uint16_t*)(smem + (size_t)b * T_STRIDE + trow * 128 + (nt * 16 + ln) * 2) =
            __half_as_ushort(__float2half(c[reg] + bias));
      }
    }
  }

  // W2 B-frags + epilogue consts (global, L2-hot) — overlaps Phase-1 tail
  f16x8 W2f[2][2];
  #pragma unroll
  for (int nt = 0; nt < 2; ++nt)
    #pragma unroll
    for (int ks = 0; ks < 2; ++ks)
      W2f[nt][ks] = *(const f16x8*)(w2t + (nt * 16 + ln) * 64 + ks * 32 + qd * 8);
  float b2v[2], w3v[2];
  #pragma unroll
  for (int nt = 0; nt < 2; ++nt) {
    b2v[nt] = b2s[nt * 16 + ln];
    w3v[nt] = w3s[nt * 16 + ln];
  }

  __syncthreads();                                    // T ready

  // ------------- Phase 2: 60 units (30 q x 2 mt) over 16 waves ------------
  const int mtw = wv & 1;
  const int qr  = wv >> 1;                            // 0..7
  const __half2 one2 = __float2half2_rn(1.0f);
  const char* Tb  = smem + (size_t)(mtw * 16 + ln) * T_STRIDE;
  const int koff  = qd * 16;

  float yacc[4] = {0.f, 0.f, 0.f, 0.f};

  #pragma unroll 2
  for (int t3 = 0; t3 < 4; ++t3) {
    const int q = qr + 8 * t3;
    if (q >= 30) break;                               // wave-uniform
    const int p  = q >> 1;
    const int iv = (int)((I_BITS >> (3 * p)) & 7ull);
    const int jv = (int)((J_BITS >> (3 * p)) & 7ull);
    const int An = (q & 1) ? jv : iv;
    const int Bn = (q & 1) ? iv : jv;
    const char* TA = Tb + (1 + An) * 128;
    const char* TB = Tb + (7 + Bn) * 128;

    union U4 { u32x4 u; __half2 h[4]; };
    U4 du0, da0, db0, du1, da1, db1;
    du0.u = *(const u32x4*)(Tb + koff);
    da0.u = *(const u32x4*)(TA + koff);
    db0.u = *(const u32x4*)(TB + koff);
    du1.u = *(const u32x4*)(Tb + 64 + koff);
    da1.u = *(const u32x4*)(TA + 64 + koff);
    db1.u = *(const u32x4*)(TB + 64 + koff);

    union { f16x8 v; __half2 h[4]; } A0, A1;
    #pragma unroll
    for (int w = 0; w < 4; ++w) A0.h[w] = h1pair(du0.h[w], da0.h[w], db0.h[w], one2);
    #pragma unroll
    for (int w = 0; w < 4; ++w) A1.h[w] = h1pair(du1.h[w], da1.h[w], db1.h[w], one2);

    f32x4 c0 = {0.f, 0.f, 0.f, 0.f};
    f32x4 c1 = {0.f, 0.f, 0.f, 0.f};
    c0 = __builtin_amdgcn_mfma_f32_16x16x32_f16(A0.v, W2f[0][0], c0, 0, 0, 0);
    c0 = __builtin_amdgcn_mfma_f32_16x16x32_f16(A1.v, W2f[0][1], c0, 0, 0, 0);
    c1 = __builtin_amdgcn_mfma_f32_16x16x32_f16(A0.v, W2f[1][0], c1, 0, 0, 0);
    c1 = __builtin_amdgcn_mfma_f32_16x16x32_f16(A1.v, W2f[1][1], c1, 0, 0, 0);

    #pragma unroll
    for (int reg = 0; reg < 4; ++reg) {
      yacc[reg] += sp2(c0[reg] + b2v[0]) * w3v[0]
                 + sp2(c1[reg] + b2v[1]) * w3v[1];
    }
  }

  // reduce over the 16 fragment columns (ln) inside each quad group
  #pragma unroll
  for (int reg = 0; reg < 4; ++reg) {
    float v = yacc[reg];
    v += __shfl_xor(v, 1);
    v += __shfl_xor(v, 2);
    v += __shfl_xor(v, 4);
    v += __shfl_xor(v, 8);
    yacc[reg] = v;
  }
  if (ln == 0) {
    #pragma unroll
    for (int reg = 0; reg < 4; ++reg)
      atomicAdd(&yred[mtw * 16 + qd * 4 + reg], yacc[reg]);
  }
  __syncthreads();
  if (tid < BPB) out[b0 + tid] = 0.5f * yred[tid] + 15.0f * b3[0];
}

extern "C" void kernel_launch(void* const* d_in, const int* in_sizes, int n_in,
                              void* d_out, int out_size, void* d_ws, size_t ws_size,
                              hipStream_t stream) {
  const float* core = (const float*)d_in[0];
  const float* ligs = (const float*)d_in[1];
  const float* W1   = (const float*)d_in[2];
  const float* b1   = (const float*)d_in[3];
  const float* W2   = (const float*)d_in[4];
  const float* b2   = (const float*)d_in[5];
  const float* W3   = (const float*)d_in[6];
  const float* b3   = (const float*)d_in[7];
  float* out = (float*)d_out;
  char*  ws  = (char*)d_ws;                 // needs WS_BYTES (29 KB) scratch

  const int B = in_sizes[0] / 64;           // 32768
  const int grid = B / BPB;                 // 1024

  prep<<<dim3(57), dim3(256), 0, stream>>>(W1, b1, W2, b2, W3, ws);

  (void)hipFuncSetAttribute((const void*)tb_fused,
                            hipFuncAttributeMaxDynamicSharedMemorySize, LDS_BYTES);
  tb_fused<<<dim3(grid), dim3(NT), LDS_BYTES, stream>>>(
      core, ligs, b3, ws, out);
}

// Round 7
// 124.932 us; speedup vs baseline: 1.1729x; 1.1729x over previous
//
#include <hip/hip_runtime.h>
#include <hip/hip_fp16.h>
#include <stdint.h>

// ---------------------------------------------------------------------------
// ThreeBodyLayer fused kernel v6 (MI355X / gfx950)
//
// All-f16 MFMA pipeline, log2-domain softplus. Scale algebra: W1/b1 carry
// log2(e); W2 carries ln2*log2(e)=1; b2*log2(e); W3*ln2.
//
// v6 vs v5 (64us, occ 77%, VALU 33%) and v4b (48us, occ 39%, VALU 43%):
//  - BPB=32 AND W1^T in LDS: T(53.8K)+W1T(27.6K)=81.5K -> 2 blocks/CU,
//    8 waves/SIMD, with B-frags on the low-latency DS pipe (v5's regression
//    came from global-fed B-frags + doubled A-loads).
//  - W1T pre-converted by prep into d_ws; block stages it with a vectorized
//    remap copy (no per-block f32->f16 conversion).
//  - Phase 1: 14 jobs = (xr 0..6) x (mt 0..1), one wave each, A loaded once.
// ---------------------------------------------------------------------------

typedef __attribute__((ext_vector_type(8))) _Float16 f16x8;
typedef __attribute__((ext_vector_type(2))) __fp16   fp16v2;   // cvt_pkrtz ret
typedef __attribute__((ext_vector_type(4))) float    f32x4;
typedef __attribute__((ext_vector_type(4))) unsigned int u32x4;

constexpr int   BPB       = 32;       // batch elems per block
constexpr int   NT        = 1024;     // 16 waves
constexpr int   T_STRIDE  = 1680;     // bytes per b: 13*128 + 16 pad
constexpr int   WT_RS     = 72;       // padded f16 row stride in LDS (2-way banks)
constexpr int   WT_OFF    = BPB * T_STRIDE;          // 53760
constexpr int   Y_OFF     = WT_OFF + 192 * WT_RS * 2; // 81408
constexpr int   LDS_BYTES = Y_OFF + 128;             // 81536 -> 2 blocks/CU

// d_ws layout (bytes) — same footprint as v5 (proven to fit ws_size)
constexpr int   WS_W1T   = 0;         // 12288 f16 compact: (slab*64+n)*64 + d
constexpr int   WS_W2T   = 24576;     //  2048 f16 : m*64 + k
constexpr int   WS_B1    = 28672;     //    64 f32 : b1 * L2E
constexpr int   WS_B2    = 28928;     //    32 f32 : b2 * L2E
constexpr int   WS_W3    = 29056;     //    32 f32 : W3 * LN2
constexpr int   WS_BYTES = 29184;

constexpr float L2E = 1.4426950408889634f;
constexpr float LN2 = 0.6931471805599453f;

// PAIRS i/j packed 3 bits per pair (15 pairs)
constexpr unsigned long long I_BITS =
  (0ull<<0)|(0ull<<3)|(0ull<<6)|(0ull<<9)|(0ull<<12)|
  (1ull<<15)|(1ull<<18)|(1ull<<21)|(1ull<<24)|
  (2ull<<27)|(2ull<<30)|(2ull<<33)|
  (3ull<<36)|(3ull<<39)|(4ull<<42);
constexpr unsigned long long J_BITS =
  (1ull<<0)|(2ull<<3)|(3ull<<6)|(4ull<<9)|(5ull<<12)|
  (2ull<<15)|(3ull<<18)|(4ull<<21)|(5ull<<24)|
  (3ull<<27)|(4ull<<30)|(5ull<<33)|
  (4ull<<36)|(5ull<<39)|(5ull<<42);

__device__ __forceinline__ float sp2(float s) {       // log2(1+exp2(s))
  float t = __builtin_amdgcn_exp2f(s);
  return __builtin_amdgcn_logf(1.0f + t);             // v_log_f32 = log2
}

__device__ __forceinline__ __half2 h1pair(__half2 u, __half2 a, __half2 b,
                                          __half2 one2) {
  __half2 s = __hadd2(__hadd2(u, a), b);
  __half2 t = h2exp2(s);                              // |s|<~8 -> safe in f16
  return h2log2(__hadd2(one2, t));
}

// ------------------------- prep: weights -> d_ws ---------------------------
__global__ __launch_bounds__(256)
void prep(const float* __restrict__ W1, const float* __restrict__ b1,
          const float* __restrict__ W2, const float* __restrict__ b2,
          const float* __restrict__ W3, char* __restrict__ ws)
{
  const int t = (int)(blockIdx.x * blockDim.x + threadIdx.x);   // 0..16383
  uint16_t* w1t = (uint16_t*)(ws + WS_W1T);
  uint16_t* w2t = (uint16_t*)(ws + WS_W2T);
  float*    b1s = (float*)(ws + WS_B1);
  float*    b2s = (float*)(ws + WS_B2);
  float*    w3s = (float*)(ws + WS_W3);
  if (t < 12288) {
    const int d = t >> 6, n = t & 63;                 // W1 is [d=192][n=64]
    const int slab = d >> 6;
    w1t[(slab * 64 + n) * 64 + (d & 63)] =
        __half_as_ushort(__float2half(W1[t] * L2E));
  } else if (t < 14336) {
    const int e = t - 12288;                          // W2 is [k=64][m=32]
    const int k = e >> 5, m = e & 31;
    w2t[m * 64 + k] = __half_as_ushort(__float2half(W2[e]));
  } else if (t < 14400) {
    b1s[t - 14336] = b1[t - 14336] * L2E;
  } else if (t < 14432) {
    b2s[t - 14400] = b2[t - 14400] * L2E;
  } else if (t < 14464) {
    w3s[t - 14432] = W3[t - 14432] * LN2;
  }
}

// ------------------------------ main kernel --------------------------------
__global__ __launch_bounds__(NT, 8)
void tb_fused(const float* __restrict__ core, const float* __restrict__ ligs,
              const float* __restrict__ b3,   const char* __restrict__ ws,
              float* __restrict__ out)
{
  extern __shared__ char smem[];
  const int tid  = (int)threadIdx.x;
  const int lane = tid & 63;
  const int ln   = lane & 15;        // fragment column
  const int qd   = lane >> 4;        // fragment quad
  const int wv   = __builtin_amdgcn_readfirstlane(tid >> 6);  // 0..15
  const int b0   = (int)blockIdx.x * BPB;

  const uint16_t* w2t = (const uint16_t*)(ws + WS_W2T);
  const float*    b1s = (const float*)(ws + WS_B1);
  const float*    b2s = (const float*)(ws + WS_B2);
  const float*    w3s = (const float*)(ws + WS_W3);

  float* yred = (float*)(smem + Y_OFF);

  // ---- stage W1T (compact ws rows of 64 halves -> LDS rows of stride 72) --
  // 3072 uint2 chunks: chunk c -> row = c>>4, col8 = c&15 (8B units)
  #pragma unroll
  for (int rep = 0; rep < 3; ++rep) {
    const int c   = tid + rep * NT;                   // < 3072 always
    const int row = c >> 4, col = c & 15;
    *(uint2*)(smem + WT_OFF + row * (WT_RS * 2) + col * 8) =
        *(const uint2*)(ws + WS_W1T + row * 128 + col * 8);
  }
  if (tid < BPB) yred[tid] = 0.0f;
  __syncthreads();                                    // barrier #1: W1T ready

  // ------------- Phase 1: 14 jobs = (xr 0..6) x (mt 0..1), 1 per wave -----
  if (wv < 14) {
    const int xr = wv >> 1;
    const int mt = wv & 1;
    const float* src = (xr == 0)
        ? (core + (size_t)(b0 + mt * 16 + ln) * 64)
        : (ligs + ((size_t)(b0 + mt * 16 + ln) * 6 + (size_t)(xr - 1)) * 64);

    union AF { f16x8 v; fp16v2 p[4]; } Afr[2];
    #pragma unroll
    for (int ks = 0; ks < 2; ++ks) {
      const float4 f0 = *(const float4*)(src + ks * 32 + qd * 8);
      const float4 f1 = *(const float4*)(src + ks * 32 + qd * 8 + 4);
      Afr[ks].p[0] = __builtin_amdgcn_cvt_pkrtz(f0.x, f0.y);
      Afr[ks].p[1] = __builtin_amdgcn_cvt_pkrtz(f0.z, f0.w);
      Afr[ks].p[2] = __builtin_amdgcn_cvt_pkrtz(f1.x, f1.y);
      Afr[ks].p[3] = __builtin_amdgcn_cvt_pkrtz(f1.z, f1.w);
    }

    const int sl_lo = (xr == 0) ? 0 : 1;
    const int sl_hi = (xr == 0) ? 0 : 2;
    #pragma unroll 1
    for (int sl = sl_lo; sl <= sl_hi; ++sl) {
      const int trow = (xr == 0) ? 0 : ((sl == 1) ? xr : 6 + xr);
      #pragma unroll
      for (int nt = 0; nt < 4; ++nt) {
        f32x4 c = {0.f, 0.f, 0.f, 0.f};
        #pragma unroll
        for (int ks = 0; ks < 2; ++ks) {
          const f16x8 Bf = *(const f16x8*)(smem + WT_OFF +
              ((sl * 64 + nt * 16 + ln) * WT_RS + ks * 32 + qd * 8) * 2);
          c = __builtin_amdgcn_mfma_f32_16x16x32_f16(Afr[ks].v, Bf, c, 0, 0, 0);
        }
        const float bias = (trow == 0) ? b1s[nt * 16 + ln] : 0.0f;
        #pragma unroll
        for (int reg = 0; reg < 4; ++reg) {
          const int b = mt * 16 + qd * 4 + reg;       // C row = batch-local b
          *(uint16_t*)(smem + (size_t)b * T_STRIDE + trow * 128 + (nt * 16 + ln) * 2) =
              __half_as_ushort(__float2half(c[reg] + bias));
        }
      }
    }
  }

  // W2 B-frags + epilogue consts (global, L2-hot) — overlaps Phase-1 tail
  f16x8 W2f[2][2];
  #pragma unroll
  for (int nt = 0; nt < 2; ++nt)
    #pragma unroll
    for (int ks = 0; ks < 2; ++ks)
      W2f[nt][ks] = *(const f16x8*)(w2t + (nt * 16 + ln) * 64 + ks * 32 + qd * 8);
  float b2v[2], w3v[2];
  #pragma unroll
  for (int nt = 0; nt < 2; ++nt) {
    b2v[nt] = b2s[nt * 16 + ln];
    w3v[nt] = w3s[nt * 16 + ln];
  }

  __syncthreads();                                    // barrier #2: T ready

  // ------------- Phase 2: 60 units (30 q x 2 mt) over 16 waves ------------
  const int mtw = wv & 1;
  const int qr  = wv >> 1;                            // 0..7
  const __half2 one2 = __float2half2_rn(1.0f);
  const char* Tb  = smem + (size_t)(mtw * 16 + ln) * T_STRIDE;
  const int koff  = qd * 16;

  float yacc[4] = {0.f, 0.f, 0.f, 0.f};

  #pragma unroll 2
  for (int t3 = 0; t3 < 4; ++t3) {
    const int q = qr + 8 * t3;
    if (q >= 30) break;                               // wave-uniform
    const int p  = q >> 1;
    const int iv = (int)((I_BITS >> (3 * p)) & 7ull);
    const int jv = (int)((J_BITS >> (3 * p)) & 7ull);
    const int An = (q & 1) ? jv : iv;
    const int Bn = (q & 1) ? iv : jv;
    const char* TA = Tb + (1 + An) * 128;
    const char* TB = Tb + (7 + Bn) * 128;

    union U4 { u32x4 u; __half2 h[4]; };
    U4 du0, da0, db0, du1, da1, db1;
    du0.u = *(const u32x4*)(Tb + koff);
    da0.u = *(const u32x4*)(TA + koff);
    db0.u = *(const u32x4*)(TB + koff);
    du1.u = *(const u32x4*)(Tb + 64 + koff);
    da1.u = *(const u32x4*)(TA + 64 + koff);
    db1.u = *(const u32x4*)(TB + 64 + koff);

    union { f16x8 v; __half2 h[4]; } A0, A1;
    #pragma unroll
    for (int w = 0; w < 4; ++w) A0.h[w] = h1pair(du0.h[w], da0.h[w], db0.h[w], one2);
    #pragma unroll
    for (int w = 0; w < 4; ++w) A1.h[w] = h1pair(du1.h[w], da1.h[w], db1.h[w], one2);

    f32x4 c0 = {0.f, 0.f, 0.f, 0.f};
    f32x4 c1 = {0.f, 0.f, 0.f, 0.f};
    c0 = __builtin_amdgcn_mfma_f32_16x16x32_f16(A0.v, W2f[0][0], c0, 0, 0, 0);
    c0 = __builtin_amdgcn_mfma_f32_16x16x32_f16(A1.v, W2f[0][1], c0, 0, 0, 0);
    c1 = __builtin_amdgcn_mfma_f32_16x16x32_f16(A0.v, W2f[1][0], c1, 0, 0, 0);
    c1 = __builtin_amdgcn_mfma_f32_16x16x32_f16(A1.v, W2f[1][1], c1, 0, 0, 0);

    #pragma unroll
    for (int reg = 0; reg < 4; ++reg) {
      yacc[reg] += sp2(c0[reg] + b2v[0]) * w3v[0]
                 + sp2(c1[reg] + b2v[1]) * w3v[1];
    }
  }

  // reduce over the 16 fragment columns (ln) inside each quad group
  #pragma unroll
  for (int reg = 0; reg < 4; ++reg) {
    float v = yacc[reg];
    v += __shfl_xor(v, 1);
    v += __shfl_xor(v, 2);
    v += __shfl_xor(v, 4);
    v += __shfl_xor(v, 8);
    yacc[reg] = v;
  }
  if (ln == 0) {
    #pragma unroll
    for (int reg = 0; reg < 4; ++reg)
      atomicAdd(&yred[mtw * 16 + qd * 4 + reg], yacc[reg]);
  }
  __syncthreads();
  if (tid < BPB) out[b0 + tid] = 0.5f * yred[tid] + 15.0f * b3[0];
}

extern "C" void kernel_launch(void* const* d_in, const int* in_sizes, int n_in,
                              void* d_out, int out_size, void* d_ws, size_t ws_size,
                              hipStream_t stream) {
  const float* core = (const float*)d_in[0];
  const float* ligs = (const float*)d_in[1];
  const float* W1   = (const float*)d_in[2];
  const float* b1   = (const float*)d_in[3];
  const float* W2   = (const float*)d_in[4];
  const float* b2   = (const float*)d_in[5];
  const float* W3   = (const float*)d_in[6];
  const float* b3   = (const float*)d_in[7];
  float* out = (float*)d_out;
  char*  ws  = (char*)d_ws;                 // needs WS_BYTES (29 KB) scratch

  const int B = in_sizes[0] / 64;           // 32768
  const int grid = B / BPB;                 // 1024

  prep<<<dim3(57), dim3(256), 0, stream>>>(W1, b1, W2, b2, W3, ws);

  (void)hipFuncSetAttribute((const void*)tb_fused,
                            hipFuncAttributeMaxDynamicSharedMemorySize, LDS_BYTES);
  tb_fused<<<dim3(grid), dim3(NT), LDS_BYTES, stream>>>(
      core, ligs, b3, ws, out);
}